// Round 4
// baseline (503.559 us; speedup 1.0000x reference)
//
#include <hip/hip_runtime.h>
#include <math.h>

typedef _Float16 f16x8 __attribute__((ext_vector_type(8)));
typedef float f32x4 __attribute__((ext_vector_type(4)));

#define SEQ 2048
#define DM 1024
#define NH 16
#define HD 64
#define MTOT 4096   // batch*seq

#define NEG_BIG (-30000.0f)

// ---------------------------------------------------------------------------
// GEMM: Y(M,N) = X(M,K) @ W(K,N). X is fp32 wire or fp16 workspace (XF16),
// W is fp32 wire (converted to fp16 while staging), fp32 MFMA accum,
// Y stored fp16 (workspace) or fp32 (final out) per OUTF32.
// 64x64 tile / block (256 thr = 4 waves, each 32x32 via 2x2 16x16x32 MFMAs).
// ---------------------------------------------------------------------------
template <bool XF16, bool OUTF32>
__global__ __launch_bounds__(256) void gemm_f16(const void* __restrict__ Xv,
                                                const float* __restrict__ W,
                                                void* __restrict__ Yv,
                                                int M, int N, int K) {
  __shared__ _Float16 Xs[64][32];   // [m][k]
  __shared__ _Float16 WTs[64][32];  // [n][k] (transposed for B-frag b128 reads)
  const int tid = threadIdx.x;
  const int lane = tid & 63;
  const int fl = lane & 15, fh = lane >> 4;
  const int wave = tid >> 6;
  const int m0 = blockIdx.y * 64;
  const int n0 = blockIdx.x * 64;
  const int wm = (wave >> 1) * 32;
  const int wn = (wave & 1) * 32;

  const int xr = tid >> 2, xc = (tid & 3) * 8;  // 64 rows x 32 cols
  const int wr = tid >> 3, wc = (tid & 7) * 8;  // 32 rows x 64 cols

  f32x4 acc[2][2] = {};

  for (int k0 = 0; k0 < K; k0 += 32) {
    f16x8 xv;
    if (XF16) {
      xv = *(const f16x8*)((const _Float16*)Xv + (size_t)(m0 + xr) * K + k0 + xc);
    } else {
      const float* Xf = (const float*)Xv + (size_t)(m0 + xr) * K + k0 + xc;
      f32x4 x0 = *(const f32x4*)Xf;
      f32x4 x1 = *(const f32x4*)(Xf + 4);
#pragma unroll
      for (int i = 0; i < 4; ++i) { xv[i] = (_Float16)x0[i]; xv[4 + i] = (_Float16)x1[i]; }
    }
    const float* Wf = W + (size_t)(k0 + wr) * N + n0 + wc;
    f32x4 w0 = *(const f32x4*)Wf;
    f32x4 w1 = *(const f32x4*)(Wf + 4);
    __syncthreads();
    *(f16x8*)(&Xs[xr][xc]) = xv;
#pragma unroll
    for (int i = 0; i < 4; ++i) {
      WTs[wc + i][wr] = (_Float16)w0[i];
      WTs[wc + 4 + i][wr] = (_Float16)w1[i];
    }
    __syncthreads();
    f16x8 a0 = *(const f16x8*)(&Xs[wm + fl][fh * 8]);
    f16x8 a1 = *(const f16x8*)(&Xs[wm + 16 + fl][fh * 8]);
    f16x8 b0 = *(const f16x8*)(&WTs[wn + fl][fh * 8]);
    f16x8 b1 = *(const f16x8*)(&WTs[wn + 16 + fl][fh * 8]);
    acc[0][0] = __builtin_amdgcn_mfma_f32_16x16x32_f16(a0, b0, acc[0][0], 0, 0, 0);
    acc[0][1] = __builtin_amdgcn_mfma_f32_16x16x32_f16(a0, b1, acc[0][1], 0, 0, 0);
    acc[1][0] = __builtin_amdgcn_mfma_f32_16x16x32_f16(a1, b0, acc[1][0], 0, 0, 0);
    acc[1][1] = __builtin_amdgcn_mfma_f32_16x16x32_f16(a1, b1, acc[1][1], 0, 0, 0);
  }

  // C/D layout: row = fh*4 + r, col = fl
#pragma unroll
  for (int mi = 0; mi < 2; ++mi)
#pragma unroll
    for (int ni = 0; ni < 2; ++ni) {
      const int gm = m0 + wm + mi * 16 + fh * 4;
      const int gn = n0 + wn + ni * 16 + fl;
#pragma unroll
      for (int r = 0; r < 4; ++r) {
        if (OUTF32)
          ((float*)Yv)[(size_t)(gm + r) * N + gn] = acc[mi][ni][r];
        else
          ((_Float16*)Yv)[(size_t)(gm + r) * N + gn] = (_Float16)acc[mi][ni][r];
      }
    }
}

// ---------------------------------------------------------------------------
// RoPE (in-place, fp16 ws): buf (batch*seq, NH, HD); pairs (2i,2i+1) per head.
// ---------------------------------------------------------------------------
__global__ __launch_bounds__(256) void rope_kernel(_Float16* __restrict__ buf) {
  const int i = blockIdx.x * 256 + threadIdx.x;  // pair id: 4096*512 total
  const int row = i >> 9;                        // b*SEQ + s
  const int p = i & 511;
  const int h = p >> 5;
  const int d2 = p & 31;
  const int s = row & (SEQ - 1);
  const float inv = __powf(10000.0f, -(float)d2 * (1.0f / 32.0f));
  const float fr = (float)s * inv;
  const float c = cosf(fr), sn = sinf(fr);
  const size_t base = (size_t)row * DM + h * HD + 2 * d2;
  const float x1 = (float)buf[base];
  const float x2 = (float)buf[base + 1];
  buf[base] = (_Float16)(x1 * c - x2 * sn);
  buf[base + 1] = (_Float16)(x1 * sn + x2 * c);
}

// ---------------------------------------------------------------------------
// Flash attention, causal, fp16 in/out (workspace). Layout (b, s, h, hd).
// Block: 256 thr = 4 waves, each wave one 16-row Q tile (block: 64 Q rows).
// O may alias Q: Q fragment is register-resident before the loop; O written
// only in the epilogue to exactly the cells this block (and no other) read.
// ---------------------------------------------------------------------------
__global__ __launch_bounds__(256) void attn_kernel(const _Float16* __restrict__ Q,
                                                   const _Float16* __restrict__ K,
                                                   const _Float16* __restrict__ V,
                                                   _Float16* __restrict__ O) {
  __shared__ _Float16 Ks[32][64];      // [kv][d]
  __shared__ _Float16 Vt[64][40];      // [d][kv] padded
  __shared__ _Float16 Pl[4][16][40];   // per-wave P tile [q][kv] padded

  const int tid = threadIdx.x;
  const int lane = tid & 63;
  const int fl = lane & 15, fh = lane >> 4;
  const int wave = tid >> 6;
  const int bh = blockIdx.y;
  const int b = bh >> 4, h = bh & 15;
  const int q0 = blockIdx.x * 64;
  const int qt = q0 + wave * 16;

  const _Float16* Qb = Q + (size_t)b * SEQ * DM + h * HD;
  const _Float16* Kb = K + (size_t)b * SEQ * DM + h * HD;
  const _Float16* Vb = V + (size_t)b * SEQ * DM + h * HD;

  const f16x8 qf0 = *(const f16x8*)(Qb + (size_t)(qt + fl) * DM + fh * 8);
  const f16x8 qf1 = *(const f16x8*)(Qb + (size_t)(qt + fl) * DM + 32 + fh * 8);

  f32x4 o_acc[4] = {};
  float m_r[4], l_r[4];
#pragma unroll
  for (int r = 0; r < 4; ++r) { m_r[r] = NEG_BIG; l_r[r] = 0.0f; }

  const float scale = 0.03125f;  // 1/sqrt(1024)
  const int kv_end = q0 + 64;
  const int sr = tid >> 3, sc = (tid & 7) * 8;  // staging: 32 rows x 64 cols

  for (int kv0 = 0; kv0 < kv_end; kv0 += 32) {
    f16x8 kvv = *(const f16x8*)(Kb + (size_t)(kv0 + sr) * DM + sc);
    f16x8 vvv = *(const f16x8*)(Vb + (size_t)(kv0 + sr) * DM + sc);
    __syncthreads();
    *(f16x8*)(&Ks[sr][sc]) = kvv;
#pragma unroll
    for (int i = 0; i < 8; ++i) Vt[sc + i][sr] = vvv[i];
    __syncthreads();

    // S = Q K^T for two 16-col tiles
    f32x4 s_t[2];
#pragma unroll
    for (int t = 0; t < 2; ++t) {
      f16x8 kf0 = *(const f16x8*)(&Ks[t * 16 + fl][fh * 8]);
      f16x8 kf1 = *(const f16x8*)(&Ks[t * 16 + fl][32 + fh * 8]);
      f32x4 z = {0.f, 0.f, 0.f, 0.f};
      z = __builtin_amdgcn_mfma_f32_16x16x32_f16(qf0, kf0, z, 0, 0, 0);
      z = __builtin_amdgcn_mfma_f32_16x16x32_f16(qf1, kf1, z, 0, 0, 0);
      s_t[t] = z;
    }

    // online softmax (rows = fh*4+r, cols = fl / 16+fl)
    float alpha[4], p0s[4], p1s[4];
#pragma unroll
    for (int r = 0; r < 4; ++r) {
      const int qg = qt + fh * 4 + r;
      float v0 = s_t[0][r] * scale;
      float v1 = s_t[1][r] * scale;
      if (kv0 + fl > qg) v0 = NEG_BIG;
      if (kv0 + 16 + fl > qg) v1 = NEG_BIG;
      float mx = fmaxf(v0, v1);
#pragma unroll
      for (int off = 1; off < 16; off <<= 1)
        mx = fmaxf(mx, __shfl_xor(mx, off, 64));
      const float mn = fmaxf(m_r[r], mx);
      const float a = __expf(m_r[r] - mn);
      const float p0 = __expf(v0 - mn);
      const float p1 = __expf(v1 - mn);
      float rs = p0 + p1;
#pragma unroll
      for (int off = 1; off < 16; off <<= 1)
        rs += __shfl_xor(rs, off, 64);
      l_r[r] = l_r[r] * a + rs;
      m_r[r] = mn;
      alpha[r] = a;
      p0s[r] = p0;
      p1s[r] = p1;
    }

#pragma unroll
    for (int ni = 0; ni < 4; ++ni)
#pragma unroll
      for (int r = 0; r < 4; ++r) o_acc[ni][r] *= alpha[r];

    // P: C-layout -> LDS -> A-layout (block-wide barrier: uniform trip count)
#pragma unroll
    for (int r = 0; r < 4; ++r) {
      Pl[wave][fh * 4 + r][fl] = (_Float16)p0s[r];
      Pl[wave][fh * 4 + r][16 + fl] = (_Float16)p1s[r];
    }
    __syncthreads();
    const f16x8 pf = *(const f16x8*)(&Pl[wave][fl][fh * 8]);

#pragma unroll
    for (int ni = 0; ni < 4; ++ni) {
      f16x8 vf = *(const f16x8*)(&Vt[ni * 16 + fl][fh * 8]);
      o_acc[ni] = __builtin_amdgcn_mfma_f32_16x16x32_f16(pf, vf, o_acc[ni], 0, 0, 0);
    }
  }

  // epilogue: O[q][d] = o_acc / l
  float inv_l[4];
#pragma unroll
  for (int r = 0; r < 4; ++r) inv_l[r] = 1.0f / l_r[r];
#pragma unroll
  for (int ni = 0; ni < 4; ++ni)
#pragma unroll
    for (int r = 0; r < 4; ++r) {
      const int qg = qt + fh * 4 + r;
      const int d = ni * 16 + fl;
      O[((size_t)b * SEQ + qg) * DM + h * HD + d] =
          (_Float16)(o_acc[ni][r] * inv_l[r]);
    }
}

// ---------------------------------------------------------------------------
extern "C" void kernel_launch(void* const* d_in, const int* in_sizes, int n_in,
                              void* d_out, int out_size, void* d_ws, size_t ws_size,
                              hipStream_t stream) {
  // Wire dtypes: reference inputs are fp16 -> harness canonicalizes to fp32;
  // reference output is fp32 -> d_out is float*.
  const float* x = (const float*)d_in[0];
  const float* qw = (const float*)d_in[1];
  const float* kw = (const float*)d_in[2];
  const float* vw = (const float*)d_in[3];
  const float* ow = (const float*)d_in[4];
  float* out = (float*)d_out;

  _Float16* Qw = (_Float16*)d_ws;
  _Float16* Kw = Qw + (size_t)MTOT * DM;
  _Float16* Vw = Kw + (size_t)MTOT * DM;
  _Float16* Mw = Qw;  // attention output aliases Q (see attn_kernel comment)

  dim3 gg(DM / 64, MTOT / 64);  // (16, 64)
  gemm_f16<false, false><<<gg, 256, 0, stream>>>(x, qw, Qw, MTOT, DM, DM);
  gemm_f16<false, false><<<gg, 256, 0, stream>>>(x, kw, Kw, MTOT, DM, DM);
  gemm_f16<false, false><<<gg, 256, 0, stream>>>(x, vw, Vw, MTOT, DM, DM);

  rope_kernel<<<(MTOT * 512) / 256, 256, 0, stream>>>(Qw);
  rope_kernel<<<(MTOT * 512) / 256, 256, 0, stream>>>(Kw);

  attn_kernel<<<dim3(SEQ / 64, 32), 256, 0, stream>>>(Qw, Kw, Vw, Mw);

  gemm_f16<true, true><<<gg, 256, 0, stream>>>(Mw, ow, out, MTOT, DM, DM);
}

// Round 5
// 291.686 us; speedup vs baseline: 1.7264x; 1.7264x over previous
//
#include <hip/hip_runtime.h>
#include <math.h>

typedef _Float16 f16x8 __attribute__((ext_vector_type(8)));
typedef float f32x4 __attribute__((ext_vector_type(4)));

#define SEQ 2048
#define DM 1024
#define NH 16
#define HD 64
#define MTOT 4096   // batch*seq

#define NEG_BIG (-30000.0f)

// ---------------------------------------------------------------------------
// fp32 -> fp16 straight convert (x): n multiple of 2048.
// ---------------------------------------------------------------------------
__global__ __launch_bounds__(256) void convert_x(const float* __restrict__ src,
                                                 _Float16* __restrict__ dst) {
  const int i = (blockIdx.x * 256 + threadIdx.x) * 8;
  f32x4 a = *(const f32x4*)(src + i);
  f32x4 b = *(const f32x4*)(src + i + 4);
  f16x8 o;
#pragma unroll
  for (int j = 0; j < 4; ++j) { o[j] = (_Float16)a[j]; o[4 + j] = (_Float16)b[j]; }
  *(f16x8*)(dst + i) = o;
}

// ---------------------------------------------------------------------------
// Weight transpose+convert: w fp32 [k][n] (1024x1024) -> wT fp16 [n][k].
// 64x64 tiles, LDS staged. grid (16,16,4) selects matrix by z.
// ---------------------------------------------------------------------------
__global__ __launch_bounds__(256) void transpose_w(const float* __restrict__ q,
                                                   const float* __restrict__ k,
                                                   const float* __restrict__ v,
                                                   const float* __restrict__ o,
                                                   _Float16* __restrict__ dstBase) {
  __shared__ float Ts[64][65];
  const float* srcs[4] = {q, k, v, o};
  const float* src = srcs[blockIdx.z];
  _Float16* dst = dstBase + (size_t)blockIdx.z * DM * DM;
  const int t = threadIdx.x;
  const int k0 = blockIdx.y * 64, n0 = blockIdx.x * 64;
  const int r = t >> 2, c4 = (t & 3) * 16;
  const float* sp = src + (size_t)(k0 + r) * DM + n0 + c4;
#pragma unroll
  for (int j = 0; j < 4; ++j) {
    f32x4 vv = *(const f32x4*)(sp + j * 4);
#pragma unroll
    for (int e = 0; e < 4; ++e) Ts[r][c4 + j * 4 + e] = vv[e];
  }
  __syncthreads();
  f16x8 o0, o1;
#pragma unroll
  for (int j = 0; j < 8; ++j) {
    o0[j] = (_Float16)Ts[c4 + j][r];
    o1[j] = (_Float16)Ts[c4 + 8 + j][r];
  }
  _Float16* dp = dst + (size_t)(n0 + r) * DM + k0 + c4;
  *(f16x8*)(dp) = o0;
  *(f16x8*)(dp + 8) = o1;
}

// ---------------------------------------------------------------------------
// GEMM: Y = A(M,K) @ BT^T where BT is fp16 [n][k]. 128x128 tile, 256 thr =
// 4 waves each 64x64 (4x4 of 16x16x32 MFMAs), BK=32, padded LDS (2-way max).
// FUSED3: BT = 3 concatenated 1024x1024 mats, Y = 3 concatenated M*1024 bufs.
// ---------------------------------------------------------------------------
template <bool FUSED3, bool OUTF32>
__global__ __launch_bounds__(256) void gemm128(const _Float16* __restrict__ A,
                                               const _Float16* __restrict__ BT,
                                               void* __restrict__ Yv,
                                               int M, int K) {
  __shared__ _Float16 As[128][40];
  __shared__ _Float16 Bs[128][40];
  const int tid = threadIdx.x;
  const int lane = tid & 63;
  const int fl = lane & 15, fh = lane >> 4;
  const int wave = tid >> 6;
  const int m0 = blockIdx.y * 128;
  int n0 = blockIdx.x * 128;
  const _Float16* Bp = BT;
  char* Yp = (char*)Yv;
  if (FUSED3) {
    const int mat = n0 >> 10;
    n0 &= 1023;
    Bp = BT + (size_t)mat * DM * DM;
    Yp += (size_t)mat * M * DM * (OUTF32 ? 4 : 2);
  }
  const int wm = (wave >> 1) * 64, wn = (wave & 1) * 64;
  const int sr = tid >> 2, sc = (tid & 3) * 8;  // 64 rows x 32 cols per rep

  f32x4 acc[4][4] = {};

  for (int k0 = 0; k0 < K; k0 += 32) {
    f16x8 a0 = *(const f16x8*)(A + (size_t)(m0 + sr) * K + k0 + sc);
    f16x8 a1 = *(const f16x8*)(A + (size_t)(m0 + 64 + sr) * K + k0 + sc);
    f16x8 b0 = *(const f16x8*)(Bp + (size_t)(n0 + sr) * K + k0 + sc);
    f16x8 b1 = *(const f16x8*)(Bp + (size_t)(n0 + 64 + sr) * K + k0 + sc);
    __syncthreads();
    *(f16x8*)(&As[sr][sc]) = a0;
    *(f16x8*)(&As[64 + sr][sc]) = a1;
    *(f16x8*)(&Bs[sr][sc]) = b0;
    *(f16x8*)(&Bs[64 + sr][sc]) = b1;
    __syncthreads();
    f16x8 af[4], bf[4];
#pragma unroll
    for (int mi = 0; mi < 4; ++mi)
      af[mi] = *(const f16x8*)(&As[wm + mi * 16 + fl][fh * 8]);
#pragma unroll
    for (int ni = 0; ni < 4; ++ni)
      bf[ni] = *(const f16x8*)(&Bs[wn + ni * 16 + fl][fh * 8]);
#pragma unroll
    for (int mi = 0; mi < 4; ++mi)
#pragma unroll
      for (int ni = 0; ni < 4; ++ni)
        acc[mi][ni] = __builtin_amdgcn_mfma_f32_16x16x32_f16(af[mi], bf[ni], acc[mi][ni], 0, 0, 0);
  }

  // C/D: row = fh*4 + r, col = fl
#pragma unroll
  for (int mi = 0; mi < 4; ++mi)
#pragma unroll
    for (int ni = 0; ni < 4; ++ni) {
      const int gm = m0 + wm + mi * 16 + fh * 4;
      const int gn = n0 + wn + ni * 16 + fl;
#pragma unroll
      for (int r = 0; r < 4; ++r) {
        if (OUTF32)
          ((float*)Yp)[(size_t)(gm + r) * DM + gn] = acc[mi][ni][r];
        else
          ((_Float16*)Yp)[(size_t)(gm + r) * DM + gn] = (_Float16)acc[mi][ni][r];
      }
    }
}

// ---------------------------------------------------------------------------
// RoPE (in-place) on Q and K in one launch: 4 adjacent pairs per thread.
// ---------------------------------------------------------------------------
__global__ __launch_bounds__(256) void rope2(_Float16* __restrict__ Q,
                                             _Float16* __restrict__ K) {
  _Float16* buf = blockIdx.y ? K : Q;
  const int i8 = (blockIdx.x * 256 + threadIdx.x) * 8;  // half offset
  const int row = i8 >> 10;
  const int col = i8 & 1023;
  const int dcol = col & 63;       // within head, multiple of 8
  const int s = row & (SEQ - 1);
  f16x8 v = *(const f16x8*)(buf + i8);
  f16x8 o;
#pragma unroll
  for (int j = 0; j < 4; ++j) {
    const int d2 = (dcol >> 1) + j;
    const float inv = __powf(10000.0f, -(float)d2 * (1.0f / 32.0f));
    const float ang = (float)s * inv;
    float c, sn;
    __sincosf(ang, &sn, &c);
    const float x1 = (float)v[2 * j];
    const float x2 = (float)v[2 * j + 1];
    o[2 * j] = (_Float16)(x1 * c - x2 * sn);
    o[2 * j + 1] = (_Float16)(x1 * sn + x2 * c);
  }
  *(f16x8*)(buf + i8) = o;
}

// ---------------------------------------------------------------------------
// Flash attention, causal. Block = 256 thr = 4 waves; block covers 128 q rows
// (32 per wave); KV chunks of 64 staged block-wide (K rows, V transposed).
// Padded LDS (+8 halfs): keeps 16-B alignment, worst-case 2-way banks.
// Fully-masked chunks skipped per-wave (uniform barriers preserved).
// ---------------------------------------------------------------------------
__global__ __launch_bounds__(256) void attn_kernel(const _Float16* __restrict__ Q,
                                                   const _Float16* __restrict__ K,
                                                   const _Float16* __restrict__ V,
                                                   _Float16* __restrict__ O) {
  __shared__ _Float16 Ks[64][72];      // [kv][d]
  __shared__ _Float16 Vt[64][72];      // [d][kv]
  __shared__ _Float16 Pl[4][32][72];   // per-wave P [q][kv]

  const int tid = threadIdx.x;
  const int lane = tid & 63;
  const int fl = lane & 15, fh = lane >> 4;
  const int wave = tid >> 6;
  const int bh = blockIdx.y;
  const int b = bh >> 4, h = bh & 15;
  const int q0 = blockIdx.x * 128;
  const int qt = q0 + wave * 32;

  const _Float16* Qb = Q + (size_t)b * SEQ * DM + h * HD;
  const _Float16* Kb = K + (size_t)b * SEQ * DM + h * HD;
  const _Float16* Vb = V + (size_t)b * SEQ * DM + h * HD;

  f16x8 qf[2][2];
#pragma unroll
  for (int mi = 0; mi < 2; ++mi)
#pragma unroll
    for (int kh = 0; kh < 2; ++kh)
      qf[mi][kh] = *(const f16x8*)(Qb + (size_t)(qt + mi * 16 + fl) * DM + kh * 32 + fh * 8);

  f32x4 o_acc[2][4] = {};
  float m_r[2][4], l_r[2][4];
#pragma unroll
  for (int mi = 0; mi < 2; ++mi)
#pragma unroll
    for (int r = 0; r < 4; ++r) { m_r[mi][r] = NEG_BIG; l_r[mi][r] = 0.0f; }

  const float scale = 0.03125f;  // 1/sqrt(1024)
  const int sr = tid >> 2, sc16 = (tid & 3) * 16;  // staging 64 rows x 64 cols

  for (int kv0 = 0; kv0 < q0 + 128; kv0 += 64) {
    f16x8 k0v = *(const f16x8*)(Kb + (size_t)(kv0 + sr) * DM + sc16);
    f16x8 k1v = *(const f16x8*)(Kb + (size_t)(kv0 + sr) * DM + sc16 + 8);
    f16x8 v0v = *(const f16x8*)(Vb + (size_t)(kv0 + sr) * DM + sc16);
    f16x8 v1v = *(const f16x8*)(Vb + (size_t)(kv0 + sr) * DM + sc16 + 8);
    __syncthreads();
    *(f16x8*)(&Ks[sr][sc16]) = k0v;
    *(f16x8*)(&Ks[sr][sc16 + 8]) = k1v;
#pragma unroll
    for (int j = 0; j < 8; ++j) {
      Vt[sc16 + j][sr] = v0v[j];
      Vt[sc16 + 8 + j][sr] = v1v[j];
    }
    __syncthreads();
    if (kv0 >= qt + 32) continue;  // fully masked for this wave
    const bool need_mask = (kv0 + 64 > qt);

    // S = Q K^T : 2 m-tiles x 4 n-tiles
    f32x4 s_t[2][4];
#pragma unroll
    for (int ni = 0; ni < 4; ++ni) {
      f16x8 kf0 = *(const f16x8*)(&Ks[ni * 16 + fl][fh * 8]);
      f16x8 kf1 = *(const f16x8*)(&Ks[ni * 16 + fl][32 + fh * 8]);
#pragma unroll
      for (int mi = 0; mi < 2; ++mi) {
        f32x4 z = {0.f, 0.f, 0.f, 0.f};
        z = __builtin_amdgcn_mfma_f32_16x16x32_f16(qf[mi][0], kf0, z, 0, 0, 0);
        z = __builtin_amdgcn_mfma_f32_16x16x32_f16(qf[mi][1], kf1, z, 0, 0, 0);
        s_t[mi][ni] = z;
      }
    }

    // online softmax; write P straight to per-wave LDS
    float alpha[2][4];
#pragma unroll
    for (int mi = 0; mi < 2; ++mi)
#pragma unroll
      for (int r = 0; r < 4; ++r) {
        const int row = qt + mi * 16 + fh * 4 + r;
        float v[4];
#pragma unroll
        for (int ni = 0; ni < 4; ++ni) {
          v[ni] = s_t[mi][ni][r] * scale;
          if (need_mask && (kv0 + ni * 16 + fl > row)) v[ni] = NEG_BIG;
        }
        float mx = fmaxf(fmaxf(v[0], v[1]), fmaxf(v[2], v[3]));
#pragma unroll
        for (int off = 1; off < 16; off <<= 1)
          mx = fmaxf(mx, __shfl_xor(mx, off, 64));
        const float mn = fmaxf(m_r[mi][r], mx);
        const float a = __expf(m_r[mi][r] - mn);
        float rs = 0.0f;
#pragma unroll
        for (int ni = 0; ni < 4; ++ni) {
          const float pv = __expf(v[ni] - mn);
          rs += pv;
          Pl[wave][mi * 16 + fh * 4 + r][ni * 16 + fl] = (_Float16)pv;
        }
#pragma unroll
        for (int off = 1; off < 16; off <<= 1)
          rs += __shfl_xor(rs, off, 64);
        l_r[mi][r] = l_r[mi][r] * a + rs;
        m_r[mi][r] = mn;
        alpha[mi][r] = a;
      }

#pragma unroll
    for (int mi = 0; mi < 2; ++mi)
#pragma unroll
      for (int ni = 0; ni < 4; ++ni)
#pragma unroll
        for (int r = 0; r < 4; ++r) o_acc[mi][ni][r] *= alpha[mi][r];

    // P (same-wave LDS round-trip): wait for our ds_writes, read A-frags
    asm volatile("s_waitcnt lgkmcnt(0)" ::: "memory");
    f16x8 pf[2][2];
#pragma unroll
    for (int mi = 0; mi < 2; ++mi)
#pragma unroll
      for (int kh = 0; kh < 2; ++kh)
        pf[mi][kh] = *(const f16x8*)(&Pl[wave][mi * 16 + fl][kh * 32 + fh * 8]);

#pragma unroll
    for (int ni = 0; ni < 4; ++ni) {
      f16x8 vf0 = *(const f16x8*)(&Vt[ni * 16 + fl][fh * 8]);
      f16x8 vf1 = *(const f16x8*)(&Vt[ni * 16 + fl][32 + fh * 8]);
#pragma unroll
      for (int mi = 0; mi < 2; ++mi) {
        o_acc[mi][ni] = __builtin_amdgcn_mfma_f32_16x16x32_f16(pf[mi][0], vf0, o_acc[mi][ni], 0, 0, 0);
        o_acc[mi][ni] = __builtin_amdgcn_mfma_f32_16x16x32_f16(pf[mi][1], vf1, o_acc[mi][ni], 0, 0, 0);
      }
    }
  }

  // epilogue
#pragma unroll
  for (int mi = 0; mi < 2; ++mi) {
    float inv_l[4];
#pragma unroll
    for (int r = 0; r < 4; ++r) inv_l[r] = 1.0f / l_r[mi][r];
#pragma unroll
    for (int ni = 0; ni < 4; ++ni)
#pragma unroll
      for (int r = 0; r < 4; ++r) {
        const int qg = qt + mi * 16 + fh * 4 + r;
        O[((size_t)b * SEQ + qg) * DM + h * HD + ni * 16 + fl] =
            (_Float16)(o_acc[mi][ni][r] * inv_l[r]);
      }
  }
}

// ---------------------------------------------------------------------------
extern "C" void kernel_launch(void* const* d_in, const int* in_sizes, int n_in,
                              void* d_out, int out_size, void* d_ws, size_t ws_size,
                              hipStream_t stream) {
  const float* x = (const float*)d_in[0];
  const float* qw = (const float*)d_in[1];
  const float* kw = (const float*)d_in[2];
  const float* vw = (const float*)d_in[3];
  const float* ow = (const float*)d_in[4];
  float* out = (float*)d_out;

  const size_t MD = (size_t)MTOT * DM;  // 4M elements
  _Float16* x16 = (_Float16*)d_ws;      // [0, 4M) ; later reused as attention M
  _Float16* wT = x16 + MD;              // [4M, 8M): qwT,kwT,vwT,owT (1M each)
  _Float16* Qw = wT + 4 * (size_t)DM * DM;  // [8M, 12M)
  _Float16* Kw = Qw + MD;               // [12M, 16M)
  _Float16* Vw = Kw + MD;               // [16M, 20M)
  _Float16* Mw = x16;                   // attention output reuses x16

  convert_x<<<MD / (256 * 8), 256, 0, stream>>>(x, x16);
  transpose_w<<<dim3(16, 16, 4), 256, 0, stream>>>(qw, kw, vw, ow, wT);

  // Fused QKV: N = 3072
  gemm128<true, false><<<dim3(24, MTOT / 128), 256, 0, stream>>>(x16, wT, Qw, MTOT, DM);

  rope2<<<dim3(MD / (256 * 8), 2), 256, 0, stream>>>(Qw, Kw);

  attn_kernel<<<dim3(SEQ / 128, 32), 256, 0, stream>>>(Qw, Kw, Vw, Mw);

  gemm128<false, true><<<dim3(8, MTOT / 128), 256, 0, stream>>>(
      Mw, wT + 3 * (size_t)DM * DM, out, MTOT, DM);
}